// Round 19
// baseline (218.423 us; speedup 1.0000x reference)
//
#include <hip/hip_runtime.h>

#define TT 20
#define HH 64
#define RSZ 32768      // fp32 S-bin range (128 KB dynamic LDS)
#define DRSZ 32768     // u8 deg-bin range (32 KB LDS, shared with RNN path)
#define NSL 64         // edge slices for S pass
#define NSLD 128       // edge slices for fused deg pass (short blocks: the
                       // per-block E/NSLD sweep is k_fused's latency tail)

typedef __attribute__((ext_vector_type(8))) short short8;   // 8 bf16 (MFMA A/B frag)
typedef __attribute__((ext_vector_type(4))) float f32x4;    // MFMA C/D frag

__device__ __forceinline__ unsigned fbits(float f) { union { float f; unsigned u; } v; v.f = f; return v.u; }
__device__ __forceinline__ float bcast(unsigned u) { union { float f; unsigned u; } v; v.u = u; return v.f; }

// trunc-split bf16 pack: lo16 = truncbf16(a), hi16 = truncbf16(b).
// v_perm_b32 does the 2x(>>16)+merge in ONE VALU op.
__device__ __forceinline__ unsigned pk_trunc(float a, float b) {
#if __has_builtin(__builtin_amdgcn_perm)
    return __builtin_amdgcn_perm(fbits(b), fbits(a), 0x07060302u);
#else
    return (fbits(a) >> 16) | (fbits(b) & 0xffff0000u);
#endif
}
// residual pack: lo parts of (a,b) after removing their trunc-bf16 hi halves
__device__ __forceinline__ unsigned pk_lo(float a, float b) {
    float ra = a - bcast(fbits(a) & 0xffff0000u);
    float rb = b - bcast(fbits(b) & 0xffff0000u);
    return pk_trunc(ra, rb);
}
union U8 { short8 s; unsigned u[4]; };
__device__ __forceinline__ short8 mk8(unsigned a, unsigned b, unsigned c, unsigned d) {
    U8 t; t.u[0] = a; t.u[1] = b; t.u[2] = c; t.u[3] = d; return t.s;
}

// Fused: blocks [0, RD*NSLD) = deg histogram via packed-u8 LDS bins; blocks >=
// RD*NSLD = swapped-operand MFMA RNN, 32 nodes/wave (two independent 16-node
// groups sharing A=W_hh). R12 evidence: RNN micro-opts (0 DS ops, 8 chains)
// left k_fused flat at ~106 µs AND RD 7->4 left it flat earlier -> both deg
// and RNN halves are ~100 µs and overlap; deg's per-block E/NSLD sweep is the
// invariant. This round: NSLD 32->128 cuts per-deg-block work 4x.
// launch_bounds floor stays 3 (6 caps VGPR at 85 -> spills, R6: 432 µs).
// No global atomics for deg (R8: 6.4M device atomics -> 100 MB fabric writes).
__global__ __launch_bounds__(256, 3) void k_fused(
    const float* __restrict__ x,
    const float* __restrict__ W_ih, const float* __restrict__ b_ih,
    const float* __restrict__ W_hh, const float* __restrict__ b_hh,
    const float* __restrict__ W_gcn, const float* __restrict__ W_fc,
    const int* __restrict__ ei, unsigned* __restrict__ degrep,
    float* __restrict__ z, int N, int E, int RD, int N4)
{
    __shared__ __align__(16) unsigned smem[8192];   // 32 KB

    const int t = threadIdx.x;
    const int RDN = RD * NSLD;

    if (blockIdx.x < RDN) {
        // ---- deg histogram: packed-u8 LDS bins, int4 = 2 edges per load ----
        unsigned* bin = smem;                       // 8192 words = 32768 u8 bins
        const int r = blockIdx.x % RD;
        const int s = blockIdx.x / RD;
        const int base = r * DRSZ;
        for (int i = t; i < DRSZ / 4; i += 256) bin[i] = 0;
        __syncthreads();
        const long long P = (long long)(E >> 1);
        const long long pb = s * P / NSLD;
        const long long pe = (s + 1) * P / NSLD;
        const int4* ei4 = (const int4*)ei;
        for (long long g = pb + t; g < pe; g += 256) {
            int4 q = ei4[g];
            unsigned u0 = (unsigned)(q.y - base);
            unsigned u1 = (unsigned)(q.w - base);
            if (u0 < DRSZ) atomicAdd(&bin[u0 >> 2], 1u << ((u0 & 3) << 3));
            if (u1 < DRSZ) atomicAdd(&bin[u1 >> 2], 1u << ((u1 & 3) << 3));
        }
        if ((E & 1) && s == NSLD - 1 && t == 0) {
            unsigned u = (unsigned)(ei[2 * (E - 1) + 1] - base);
            if (u < DRSZ) atomicAdd(&bin[u >> 2], 1u << ((u & 3) << 3));
        }
        __syncthreads();
        const int lim = min(DRSZ, N - base);
        const int words = (lim + 3) >> 2;
        unsigned* dst = degrep + (size_t)s * N4 + (base >> 2);
        for (int i = t; i < words; i += 256) dst[i] = bin[i];
        return;
    }

    // ---- MFMA RNN: 4 waves x 32 nodes (2 groups of 16), h in registers ----
    const int w    = t >> 6;
    const int l    = t & 63;
    const int nl   = l & 15;        // node slot within group (B col / C col)
    const int quad = l >> 4;
    const int n0   = (blockIdx.x - RDN) * 128 + w * 32;

    float* sx = (float*)&smem[w * 640];   // [20][32] f32, wave-private

    // stage x transposed [step][node], 32 nodes
    for (int i = l; i < 32 * TT; i += 64) {
        int nn = i / TT, tt = i - nn * TT;
        int n = n0 + nn; if (n >= N) n = N - 1;
        sx[tt * 32 + nn] = x[(size_t)n * TT + tt];
    }

    // A = W_hh, hi/lo trunc-split, PERMUTED k-gather (shared by both groups):
    // element e of frag (tt2,kc) at lane (nl,quad) =
    //   W_hh[16*tt2+nl][16*(2*(e>>2)+kc) + 4*quad + (e&3)]
    short8 AWh[4][2], AWl[4][2];
#pragma unroll
    for (int tt2 = 0; tt2 < 4; ++tt2)
#pragma unroll
        for (int kc = 0; kc < 2; ++kc) {
            const float* wr = W_hh + (size_t)(16 * tt2 + nl) * HH + 16 * kc + 4 * quad;
            float4 w0 = *(const float4*)wr;          // cols 16kc+4q+(0..3)
            float4 w1 = *(const float4*)(wr + 32);   // cols 32+16kc+4q+(0..3)
            AWh[tt2][kc] = mk8(pk_trunc(w0.x, w0.y), pk_trunc(w0.z, w0.w),
                               pk_trunc(w1.x, w1.y), pk_trunc(w1.z, w1.w));
            AWl[tt2][kc] = mk8(pk_lo(w0.x, w0.y), pk_lo(w0.z, w0.w),
                               pk_lo(w1.x, w1.y), pk_lo(w1.z, w1.w));
        }

    // per-lane out-feature constants: o = 16*tt2 + 4*quad + r (shared by groups)
    float wl_ = W_ih[l];
    float bl_ = b_ih[l] + b_hh[l];
    float wihf[4][4], bsf[4][4];
#pragma unroll
    for (int tt2 = 0; tt2 < 4; ++tt2)
#pragma unroll
        for (int r = 0; r < 4; ++r) {
            int o = 16 * tt2 + 4 * quad + r;
            wihf[tt2][r] = __shfl(wl_, o, 64);
            bsf[tt2][r]  = __shfl(bl_, o, 64);
        }

    f32x4 C[2][4];
    short8 Bh[2][2], Bl[2][2];
#pragma unroll
    for (int g = 0; g < 2; ++g)
#pragma unroll
        for (int kc = 0; kc < 2; ++kc) { Bh[g][kc] = mk8(0,0,0,0); Bl[g][kc] = mk8(0,0,0,0); }

    for (int step = 0; step < TT; ++step) {
        const float xv0 = sx[step * 32 + nl];
        const float xv1 = sx[step * 32 + 16 + nl];
#pragma unroll
        for (int tt2 = 0; tt2 < 4; ++tt2)
#pragma unroll
            for (int r = 0; r < 4; ++r) {
                C[0][tt2][r] = fmaf(xv0, wihf[tt2][r], bsf[tt2][r]);
                C[1][tt2][r] = fmaf(xv1, wihf[tt2][r], bsf[tt2][r]);
            }

#pragma unroll
        for (int kc = 0; kc < 2; ++kc)
#pragma unroll
            for (int tt2 = 0; tt2 < 4; ++tt2)
#pragma unroll
                for (int g = 0; g < 2; ++g) {
                    C[g][tt2] = __builtin_amdgcn_mfma_f32_16x16x32_bf16(AWh[tt2][kc], Bh[g][kc], C[g][tt2], 0, 0, 0);
                    C[g][tt2] = __builtin_amdgcn_mfma_f32_16x16x32_bf16(AWh[tt2][kc], Bl[g][kc], C[g][tt2], 0, 0, 0);
                    C[g][tt2] = __builtin_amdgcn_mfma_f32_16x16x32_bf16(AWl[tt2][kc], Bh[g][kc], C[g][tt2], 0, 0, 0);
                }

        // tanh = 1 - 2*rcp(exp2(2.885*a)+1), in place
#pragma unroll
        for (int g = 0; g < 2; ++g)
#pragma unroll
            for (int tt2 = 0; tt2 < 4; ++tt2)
#pragma unroll
                for (int r = 0; r < 4; ++r) {
                    float eg = __builtin_amdgcn_exp2f(C[g][tt2][r] * 2.885390081777927f);
                    C[g][tt2][r] = fmaf(-2.0f, __builtin_amdgcn_rcpf(eg + 1.0f), 1.0f);
                }

        // h -> next-step B frags: purely local packs (no shuffle, no LDS)
        if (step != TT - 1) {
#pragma unroll
            for (int g = 0; g < 2; ++g)
#pragma unroll
                for (int kc = 0; kc < 2; ++kc) {
                    Bh[g][kc] = mk8(pk_trunc(C[g][kc][0],     C[g][kc][1]),
                                    pk_trunc(C[g][kc][2],     C[g][kc][3]),
                                    pk_trunc(C[g][2 + kc][0], C[g][2 + kc][1]),
                                    pk_trunc(C[g][2 + kc][2], C[g][2 + kc][3]));
                    Bl[g][kc] = mk8(pk_lo(C[g][kc][0],     C[g][kc][1]),
                                    pk_lo(C[g][kc][2],     C[g][kc][3]),
                                    pk_lo(C[g][2 + kc][0], C[g][2 + kc][1]),
                                    pk_lo(C[g][2 + kc][2], C[g][2 + kc][3]));
                }
        }
    }

    // epilogue: z[n] = sum_f h[f][n] * v[f],  v = W_gcn^T w_fc
    float vl = 0.0f;
#pragma unroll 8
    for (int j = 0; j < HH; ++j) vl = fmaf(W_fc[j], W_gcn[j * HH + l], vl);

    float p0 = 0.0f, p1 = 0.0f;
#pragma unroll
    for (int tt2 = 0; tt2 < 4; ++tt2)
#pragma unroll
        for (int r = 0; r < 4; ++r) {
            float vv = __shfl(vl, 16 * tt2 + 4 * quad + r, 64);
            p0 = fmaf(C[0][tt2][r], vv, p0);
            p1 = fmaf(C[1][tt2][r], vv, p1);
        }
    p0 += __shfl_xor(p0, 16, 64); p0 += __shfl_xor(p0, 32, 64);
    p1 += __shfl_xor(p1, 16, 64); p1 += __shfl_xor(p1, 32, 64);
    if (l < 16) {
        int n = n0 + l;
        if (n < N) z[n] = p0;
    } else if (l < 32) {
        int n = n0 + 16 + nl;
        if (n < N) z[n] = p1;
    }
}

// reduce packed-u8 deg replicas; dinv = rsqrt(deg+1); w = dinv*z
__global__ __launch_bounds__(256) void k_w(const unsigned* __restrict__ degrep,
                                           const float* __restrict__ z,
                                           float* __restrict__ dinv,
                                           float* __restrict__ w, int N, int N4) {
    int n = blockIdx.x * blockDim.x + threadIdx.x;
    if (n >= N) return;
    const int wd = n >> 2, sh = (n & 3) << 3;
    unsigned d = 0;
#pragma unroll 8
    for (int s = 0; s < NSLD; ++s) d += (degrep[(size_t)s * N4 + wd] >> sh) & 0xffu;
    float di = __frsqrt_rn((float)d + 1.0f);
    dinv[n] = di;
    w[n] = di * z[n];
}

// S aggregation via fp32 LDS bins (128 KB dynamic LDS); int4 = 2 edges per load.
__global__ __launch_bounds__(1024) void k_edge_bin(const int* __restrict__ ei,
                                                   const float* __restrict__ w,
                                                   float* __restrict__ Srep,
                                                   int N, int E, int R) {
    extern __shared__ float bin[];                // RSZ floats = 128 KB
    const int r = blockIdx.x % R;
    const int s = blockIdx.x / R;
    const int base = r * RSZ;
    for (int i = threadIdx.x; i < RSZ; i += 1024) bin[i] = 0.0f;
    __syncthreads();
    const long long P = (long long)(E >> 1);
    const long long pb = s * P / NSL;
    const long long pe = (s + 1) * P / NSL;
    const int4* ei4 = (const int4*)ei;
    for (long long g = pb + threadIdx.x; g < pe; g += 1024) {
        int4 q = ei4[g];
        unsigned u0 = (unsigned)(q.y - base);
        unsigned u1 = (unsigned)(q.w - base);
        if (u0 < RSZ) atomicAdd(&bin[u0], w[q.x]);
        if (u1 < RSZ) atomicAdd(&bin[u1], w[q.z]);
    }
    if ((E & 1) && s == NSL - 1 && threadIdx.x == 0) {
        unsigned u = (unsigned)(ei[2 * (E - 1) + 1] - base);
        if (u < RSZ) atomicAdd(&bin[u], w[ei[2 * (E - 1)]]);
    }
    __syncthreads();
    const int lim = min(RSZ, N - base);
    float* dst = Srep + (size_t)s * N + base;
    for (int i = threadIdx.x; i < lim; i += 1024) dst[i] = bin[i];
}

// out = dinv*(sum S_rep) + dinv*w + c,  c = w_fc.b_gcn + b_fc
__global__ __launch_bounds__(256) void k_final(const float* __restrict__ dinv,
                                               const float* __restrict__ Srep,
                                               const float* __restrict__ w,
                                               const float* __restrict__ b_gcn,
                                               const float* __restrict__ W_fc,
                                               const float* __restrict__ b_fc,
                                               float* __restrict__ out, int N)
{
    float c = b_fc[0];
#pragma unroll 8
    for (int j = 0; j < HH; ++j) c = fmaf(W_fc[j], b_gcn[j], c);
    int n = blockIdx.x * blockDim.x + threadIdx.x;
    if (n >= N) return;
    float S = 0.0f;
#pragma unroll 8
    for (int s = 0; s < NSL; ++s) S += Srep[(size_t)s * N + n];
    float d = dinv[n];
    out[n] = fmaf(d, S, fmaf(d, w[n], c));
}

extern "C" void kernel_launch(void* const* d_in, const int* in_sizes, int n_in,
                              void* d_out, int out_size, void* d_ws, size_t ws_size,
                              hipStream_t stream)
{
    const float* x     = (const float*)d_in[0];
    const int*   ei    = (const int*)d_in[1];
    const float* W_ih  = (const float*)d_in[2];
    const float* b_ih  = (const float*)d_in[3];
    const float* W_hh  = (const float*)d_in[4];
    const float* b_hh  = (const float*)d_in[5];
    const float* W_gcn = (const float*)d_in[6];
    const float* b_gcn = (const float*)d_in[7];
    const float* W_fc  = (const float*)d_in[8];
    const float* b_fc  = (const float*)d_in[9];
    float* out = (float*)d_out;

    const int N  = in_sizes[0] / TT;
    const int E  = in_sizes[1] / 2;
    const int N4 = (N + 3) / 4;
    const int RD = (N + DRSZ - 1) / DRSZ;      // deg ranges (u8 bins, 32 KB)
    const int RS = (N + RSZ - 1) / RSZ;        // S ranges (fp32 bins, 128 KB)

    // allow 128 KB dynamic LDS for k_edge_bin (host-side, graph-capture-safe)
    static bool s_attr = false;
    if (!s_attr) {
        hipFuncSetAttribute((const void*)k_edge_bin,
                            hipFuncAttributeMaxDynamicSharedMemorySize, RSZ * 4);
        s_attr = true;
    }

    char* ws = (char*)d_ws;
    size_t off = 0;
    auto alloc = [&](size_t bytes) { void* p = ws + off; off += (bytes + 255) & ~(size_t)255; return p; };
    unsigned* degrep = (unsigned*)alloc((size_t)NSLD * N4 * 4);  // packed u8 quads
    float*    Srep   = (float*)   alloc((size_t)NSL * N * 4);
    float*    z      = (float*)   alloc((size_t)N * 4);
    float*    dinv   = (float*)   alloc((size_t)N * 4);
    float*    w      = (float*)   alloc((size_t)N * 4);
    // no memsets: every replica byte is overwritten by its (range, slice) owner

    const int rnnBlocks = (N + 127) / 128;
    k_fused   <<<RD * NSLD + rnnBlocks, 256, 0, stream>>>(x, W_ih, b_ih, W_hh, b_hh,
                                                          W_gcn, W_fc, ei, degrep,
                                                          z, N, E, RD, N4);
    k_w       <<<(N + 255) / 256, 256, 0, stream>>>(degrep, z, dinv, w, N, N4);
    k_edge_bin<<<RS * NSL, 1024, RSZ * 4, stream>>>(ei, w, Srep, N, E, RS);
    k_final   <<<(N + 255) / 256, 256, 0, stream>>>(dinv, Srep, w, b_gcn, W_fc, b_fc, out, N);
}